// Round 3
// baseline (286.101 us; speedup 1.0000x reference)
//
#include <hip/hip_runtime.h>

// 3x3 conv, stride 1, pad 1, NCHW/OIHW fp32. N=16, C=32, OC=32, H=W=256.
//
// R6: sliding-window row pipeline (duty-cycle fix).
//  - 512 blocks (16 n x 32 strips of 8 rows), 512 thr, 2 blocks/CU, whole
//    grid co-resident. Each block streams 8 output rows.
//  - ring of 3 staged input rows, full 32 ic per row record (stride 36 ush
//    = 72B: 64B data + 8B pad; frag reads land on even banks 4/bank for
//    b64 = conflict-free; 8B-aligned).
//  - per iter: issue loads row h+2 -> MFMA row h -> NT-store row h ->
//    barrier -> cvtpk+write row h+2 into retiring slot -> barrier.
//    Loads are in flight across the whole compute phase (T14).
//  - each input row loaded ONCE per block (R5 loaded each row 2x).
//  - A-frags (K-half0) hoisted to 36 VGPR: -25% LDS-pipe reads.
//  - weights staged once per 8 rows from prepped d_ws image (int4 copy).

constexpr int N_  = 16;
constexpr int C_  = 32;
constexpr int OC_ = 32;
constexpr int H_  = 256;
constexpr int W_  = 256;

constexpr int ROWS = 8;              // output rows per block
constexpr int XSTR = 36;             // ushorts per wi: 64B (32 ic) + 8B pad
constexpr int XROW = 258 * XSTR;     // 9288 ushorts per staged input row
constexpr int WSTRD = 36;            // ushorts per (t9,oc): 64B data + 8B pad
constexpr int WELEMS = 9 * 32 * WSTRD;   // 10368 ushorts
constexpr int WBYTES = WELEMS * 2;       // 20736 B (= 1296 x 16B)

typedef __attribute__((ext_vector_type(4)))  short short4v;
typedef __attribute__((ext_vector_type(8)))  short short8v;
typedef __attribute__((ext_vector_type(16))) float float16v;

static __device__ __forceinline__ unsigned short f2bf(float f) {
    unsigned int u = __float_as_uint(f);
    unsigned int r = (u + 0x7FFFu + ((u >> 16) & 1u)) >> 16;   // RNE
    return (unsigned short)r;
}

// one instruction: dst.lo16 = bf16(lo), dst.hi16 = bf16(hi)
static __device__ __forceinline__ unsigned cvtpk(float lo, float hi) {
    unsigned r;
    asm("v_cvt_pk_bf16_f32 %0, %1, %2" : "=v"(r) : "v"(lo), "v"(hi));
    return r;
}

static __device__ __forceinline__ short8v load8(const unsigned short* p) {
    // 8B-aligned: two ds_read_b64
    short4v lo = *(const short4v*)p;
    short4v hi = *(const short4v*)(p + 4);
    return __builtin_shufflevector(lo, hi, 0, 1, 2, 3, 4, 5, 6, 7);
}

// ---- prep: swizzled bf16 weight image, computed once per launch ----
__global__ void conv_w_prep(const float* __restrict__ wgt,
                            unsigned short* __restrict__ wp) {
    const int i = blockIdx.x * 256 + threadIdx.x;
    if (i >= OC_ * C_ * 9) return;
    const float v = wgt[i];
    const int oc  = i / 288;
    const int rem = i - oc * 288;
    const int ic  = rem / 9;
    const int t9  = rem - ic * 9;
    wp[(t9 * 32 + oc) * WSTRD + ic] = f2bf(v);
}

template<bool USE_WS>
__global__ __launch_bounds__(512, 4) void conv3x3_mfma_kernel(
    const float* __restrict__ x,     // [N][C][H][W]
    const float* __restrict__ wgt,   // [OC][C][3][3]
    const float* __restrict__ bias,  // [OC]
    const unsigned short* __restrict__ wpk,  // prepped weights (d_ws)
    float* __restrict__ out)         // [N][OC][H][W]
{
    __shared__ __align__(16) unsigned short ldsX[3 * XROW];   // 55,728 B
    __shared__ __align__(16) unsigned short ldsW[WELEMS];     // 20,736 B

    const int tid = threadIdx.x;

    // XCD-aware swizzle: 512 blocks, 8 XCDs x 64 consecutive strips.
    const int id = blockIdx.x;
    const int L  = (id & 7) * 64 + (id >> 3);
    const int n  = L >> 5;                  // image 0..15
    const int h0 = (L & 31) * ROWS;         // strip base row

    const int lane = tid & 63;
    const int wv   = tid >> 6;       // wave 0..7
    const int col  = lane & 31;      // A: oc; B/D: w col
    const int qd   = lane >> 5;      // k-quad select
    const int w0   = wv * 32;        // wave's 32-wide w tile

    // staging map: wlo = w-pair lane, icp = ic pair (0..15)
    const int wlo = tid & 31;
    const int icp = tid >> 5;
    const size_t HW = (size_t)H_ * W_;

    const float* xrow0 = x + (size_t)(n * C_ + 2 * icp) * HW;   // plane 2icp
    const float* xrow1 = xrow0 + HW;                            // plane 2icp+1

    // in-flight staging regs for the main loop
    float2 ra[4], rb[4];
    auto load_row = [&](int hy) {
        if (hy >= 0 && hy < H_) {
            const float* p0 = xrow0 + (size_t)hy * W_;
            const float* p1 = xrow1 + (size_t)hy * W_;
            #pragma unroll
            for (int wb = 0; wb < 4; ++wb) {
                const int w = wb * 64 + 2 * wlo;
                ra[wb] = *(const float2*)(p0 + w);
                rb[wb] = *(const float2*)(p1 + w);
            }
        } else {
            #pragma unroll
            for (int wb = 0; wb < 4; ++wb) {
                ra[wb] = make_float2(0.f, 0.f);
                rb[wb] = make_float2(0.f, 0.f);
            }
        }
    };
    auto write_row = [&](int slot) {
        unsigned short* dst = &ldsX[slot * XROW];
        #pragma unroll
        for (int wb = 0; wb < 4; ++wb) {
            const int w = wb * 64 + 2 * wlo;
            *(unsigned*)&dst[(w + 1) * XSTR + 2 * icp] = cvtpk(ra[wb].x, rb[wb].x);
            *(unsigned*)&dst[(w + 2) * XSTR + 2 * icp] = cvtpk(ra[wb].y, rb[wb].y);
        }
    };

    // ---- prologue: load rows h0-1, h0, h0+1 (all in flight), stage W ----
    float2 qa[3][4], qb[3][4];
    #pragma unroll
    for (int rr = 0; rr < 3; ++rr) {
        const int hy = h0 - 1 + rr;
        if (hy >= 0 && hy < H_) {
            const float* p0 = xrow0 + (size_t)hy * W_;
            const float* p1 = xrow1 + (size_t)hy * W_;
            #pragma unroll
            for (int wb = 0; wb < 4; ++wb) {
                const int w = wb * 64 + 2 * wlo;
                qa[rr][wb] = *(const float2*)(p0 + w);
                qb[rr][wb] = *(const float2*)(p1 + w);
            }
        } else {
            #pragma unroll
            for (int wb = 0; wb < 4; ++wb) {
                qa[rr][wb] = make_float2(0.f, 0.f);
                qb[rr][wb] = make_float2(0.f, 0.f);
            }
        }
    }

    if (USE_WS) {
        const int4* src = (const int4*)wpk;
        int4* dstW = (int4*)&ldsW[0];
        #pragma unroll
        for (int i2 = 0; i2 < 3; ++i2) {
            const int idx = tid + i2 * 512;
            if (idx < WBYTES / 16) dstW[idx] = src[idx];
        }
    } else {
        for (int i = tid; i < OC_ * C_ * 9; i += 512) {
            const float v = wgt[i];
            const int oc  = i / 288;
            const int rem = i - oc * 288;
            const int ic  = rem / 9;
            const int t9  = rem - ic * 9;
            ldsW[(t9 * 32 + oc) * WSTRD + ic] = f2bf(v);
        }
    }

    // write the three prologue rows into slots 0,1,2 (slot(r) = (r+1-h0)%3)
    #pragma unroll
    for (int rr = 0; rr < 3; ++rr) {
        unsigned short* dst = &ldsX[rr * XROW];
        #pragma unroll
        for (int wb = 0; wb < 4; ++wb) {
            const int w = wb * 64 + 2 * wlo;
            *(unsigned*)&dst[(w + 1) * XSTR + 2 * icp] = cvtpk(qa[rr][wb].x, qb[rr][wb].x);
            *(unsigned*)&dst[(w + 2) * XSTR + 2 * icp] = cvtpk(qa[rr][wb].y, qb[rr][wb].y);
        }
    }
    // halo columns wi=0 (w=-1), wi=257 (w=256): zero once; row stages never
    // touch them (they write wi 1..256 only), so this persists all 8 iters.
    if (tid < 108) {
        const int slot = tid / 36;
        const int q    = tid - slot * 36;
        const int wi   = (q >= 18) ? 257 : 0;
        const int dw   = (q >= 18) ? q - 18 : q;
        ((unsigned*)&ldsX[slot * XROW + wi * XSTR])[dw] = 0u;
    }
    __syncthreads();

    // hoist A-frags for K-half0 (9 x short8v = 36 VGPR) + bias
    short8v a0f[9];
    #pragma unroll
    for (int t9 = 0; t9 < 9; ++t9)
        a0f[t9] = load8(&ldsW[(t9 * 32 + col) * WSTRD + qd * 8]);
    float bv[16];
    #pragma unroll
    for (int r = 0; r < 16; ++r)
        bv[r] = bias[(r & 3) + 8 * (r >> 2) + 4 * qd];

    // ---- main loop: one output row per iteration ----
    #pragma unroll
    for (int it = 0; it < ROWS; ++it) {
        const int h = h0 + it;
        const bool stg = (it < ROWS - 1);
        if (stg) load_row(h + 2);        // in flight across MFMA phase

        float16v acc;
        #pragma unroll
        for (int r = 0; r < 16; ++r) acc[r] = bv[r];

        #pragma unroll
        for (int kh = 0; kh < 3; ++kh) {
            const unsigned short* bb = &ldsX[((it + kh) % 3) * XROW];
            #pragma unroll
            for (int kw = 0; kw < 3; ++kw) {
                const int t9 = kh * 3 + kw;
                const int wi = w0 + col + kw;
                const short8v b0 = load8(&bb[wi * XSTR + qd * 8]);
                acc = __builtin_amdgcn_mfma_f32_32x32x16_bf16(a0f[t9], b0, acc, 0, 0, 0);
                const short8v a1 = load8(&ldsW[(t9 * 32 + col) * WSTRD + 16 + qd * 8]);
                const short8v b1 = load8(&bb[wi * XSTR + 16 + qd * 8]);
                acc = __builtin_amdgcn_mfma_f32_32x32x16_bf16(a1, b1, acc, 0, 0, 0);
            }
        }

        // store row h (D row = oc, col = w; verified mapping)
        float* outp = out + (size_t)n * OC_ * HW + (size_t)h * W_;
        #pragma unroll
        for (int r = 0; r < 16; ++r) {
            const int oc = (r & 3) + 8 * (r >> 2) + 4 * qd;
            __builtin_nontemporal_store(acc[r], &outp[(size_t)oc * HW + w0 + col]);
        }

        if (stg) {
            __syncthreads();             // all reads of retiring slot done
            write_row(it % 3);           // row h+2 -> slot that held row h-1
            __syncthreads();             // visible for iter it+1
        }
    }
}

extern "C" void kernel_launch(void* const* d_in, const int* in_sizes, int n_in,
                              void* d_out, int out_size, void* d_ws, size_t ws_size,
                              hipStream_t stream) {
    const float* x    = (const float*)d_in[0];
    const float* wgt  = (const float*)d_in[1];
    const float* bias = (const float*)d_in[2];
    float* out        = (float*)d_out;

    dim3 grid(N_ * H_ / ROWS);   // 512 blocks: one per (n, 8-row strip)
    dim3 block(512);

    if (d_ws != nullptr && ws_size >= (size_t)WBYTES) {
        unsigned short* wp = (unsigned short*)d_ws;
        conv_w_prep<<<dim3(36), dim3(256), 0, stream>>>(wgt, wp);
        conv3x3_mfma_kernel<true><<<grid, block, 0, stream>>>(x, wgt, bias, wp, out);
    } else {
        conv3x3_mfma_kernel<false><<<grid, block, 0, stream>>>(x, wgt, bias, nullptr, out);
    }
}

// Round 4
// 242.728 us; speedup vs baseline: 1.1787x; 1.1787x over previous
//
#include <hip/hip_runtime.h>

// 3x3 conv, stride 1, pad 1, NCHW/OIHW fp32. N=16, C=32, OC=32, H=W=256.
//
// R7 = R5 structure (best: 83 us) + LDS-transposed epilogue for fully
// contiguous 1KB NT stores.
//  Evidence (R4/R5/R6): dur == hbm_bytes / 2.4 TB/s in all three rounds ->
//  pure BW wall at 2.4 TB/s. R5 bytes are near floor (134 MB write + 65 MB
//  fetch). Theory: the wall is write-stream DRAM locality -- old epilogue
//  issued NT stores of 2x128B fragments scattered across 32 oc planes
//  (256 KB apart); fragments of one output row arrived from 4 waves.
//  R6's WRITE_SIZE inflation (131->187 MB when fragments shrank) is direct
//  evidence of HBM-level fragmentation cost.
//  Fix: after last MFMA, dump accs to 32 KB LDS scratch [32 oc][256 w]
//  (reuses ldsX), then each wave stores ONE full 1KB contiguous oc-row per
//  instruction (64 lanes x float4, NT) -- same pattern as the 6.3 TB/s
//  copy benchmark. Two passes: row h, row h+1.
//
//  Unchanged from R5 (verified): 2 output rows/block, 512 thr, 2 blocks/CU,
//  XSTR=20/WSTRD=36 LDS strides (2-way-free frag reads), prepped bf16
//  weights in d_ws, v_cvt_pk_bf16_f32 pack, half1 loads under mfma half0.

constexpr int N_  = 16;
constexpr int C_  = 32;
constexpr int OC_ = 32;
constexpr int H_  = 256;
constexpr int W_  = 256;

constexpr int XSTR = 20;             // ushorts per wi: 32B data (16 ic) + 8B pad
constexpr int XROW = 258 * XSTR;     // ushorts per staged row (wi = w+1)
constexpr int WSTRD = 36;            // ushorts per (t9,oc): 64B data + 8B pad
constexpr int WELEMS = 9 * 32 * WSTRD;   // 10368 ushorts
constexpr int WBYTES = WELEMS * 2;       // 20736 B (= 1296 x 16B exactly)

typedef __attribute__((ext_vector_type(4)))  short short4v;
typedef __attribute__((ext_vector_type(8)))  short short8v;
typedef __attribute__((ext_vector_type(16))) float float16v;
typedef __attribute__((ext_vector_type(4)))  float floatx4;

static __device__ __forceinline__ unsigned short f2bf(float f) {
    unsigned int u = __float_as_uint(f);
    unsigned int r = (u + 0x7FFFu + ((u >> 16) & 1u)) >> 16;   // RNE
    return (unsigned short)r;
}

// one instruction: dst.lo16 = bf16(lo), dst.hi16 = bf16(hi)
static __device__ __forceinline__ unsigned cvtpk(float lo, float hi) {
    unsigned r;
    asm("v_cvt_pk_bf16_f32 %0, %1, %2" : "=v"(r) : "v"(lo), "v"(hi));
    return r;
}

static __device__ __forceinline__ short8v load8(const unsigned short* p) {
    // 8B-aligned: two ds_read_b64
    short4v lo = *(const short4v*)p;
    short4v hi = *(const short4v*)(p + 4);
    return __builtin_shufflevector(lo, hi, 0, 1, 2, 3, 4, 5, 6, 7);
}

// ---- prep: swizzled bf16 weight image, computed once per launch ----
__global__ void conv_w_prep(const float* __restrict__ wgt,
                            unsigned short* __restrict__ wp) {
    const int i = blockIdx.x * 256 + threadIdx.x;
    if (i >= OC_ * C_ * 9) return;
    const float v = wgt[i];
    const int oc  = i / 288;
    const int rem = i - oc * 288;
    const int ic  = rem / 9;
    const int t9  = rem - ic * 9;
    wp[(t9 * 32 + oc) * WSTRD + ic] = f2bf(v);
}

template<bool USE_WS>
__global__ __launch_bounds__(512, 4) void conv3x3_mfma_kernel(
    const float* __restrict__ x,     // [N][C][H][W]
    const float* __restrict__ wgt,   // [OC][C][3][3]
    const float* __restrict__ bias,  // [OC]
    const unsigned short* __restrict__ wpk,  // prepped weights (d_ws)
    float* __restrict__ out)         // [N][OC][H][W]
{
    __shared__ __align__(16) unsigned short ldsX[4 * XROW];   // 41,280 B
    __shared__ __align__(16) unsigned short ldsW[WELEMS];     // 20,736 B

    const int tid = threadIdx.x;

    // XCD-aware swizzle: 2048 blocks, 8 XCDs x 256 consecutive (n, h-pair).
    const int id = blockIdx.x;
    const int L  = (id & 7) * 256 + (id >> 3);
    const int n  = L >> 7;           // image 0..15
    const int h  = (L & 127) * 2;    // output rows h, h+1

    const int lane = tid & 63;
    const int wv   = tid >> 6;       // wave 0..7
    const int rsel = wv >> 2;        // output row select (0/1)
    const int col  = lane & 31;      // A: oc; B/D: w col
    const int qd   = lane >> 5;      // k-quad select
    const int w0a  = (wv & 3) * 64;
    const int w0b  = (wv & 3) * 64 + 32;

    // staging map: thread -> (staged row r4, w-pair wlo, ic-quad icq)
    const int r4  = tid >> 7;        // staged input row 0..3 (= h-1+r4)
    const int t7  = tid & 127;
    const int wlo = t7 & 31;         // w-pair lane
    const int icq = t7 >> 5;         // 0..3 (handles ic-pairs icq and icq+4)
    const size_t HW = (size_t)H_ * W_;

    // ---- issue half0 x loads first (earliest possible) ----
    float2 a0[4], a1[4], b0r[4], b1r[4];
    auto load_half = [&](int half) {
        const int icg0 = half * 16 + 2 * icq;
        const int icg1 = half * 16 + 2 * (icq + 4);
        const int hy = h - 1 + r4;
        if (hy >= 0 && hy < H_) {
            const float* pA0 = x + ((size_t)(n * C_ + icg0) * H_ + hy) * W_;
            const float* pA1 = pA0 + HW;
            const float* pB0 = x + ((size_t)(n * C_ + icg1) * H_ + hy) * W_;
            const float* pB1 = pB0 + HW;
            #pragma unroll
            for (int wb = 0; wb < 4; ++wb) {
                const int w = wb * 64 + 2 * wlo;
                a0[wb]  = *(const float2*)(pA0 + w);
                a1[wb]  = *(const float2*)(pA1 + w);
                b0r[wb] = *(const float2*)(pB0 + w);
                b1r[wb] = *(const float2*)(pB1 + w);
            }
        } else {
            #pragma unroll
            for (int wb = 0; wb < 4; ++wb) {
                a0[wb] = a1[wb] = b0r[wb] = b1r[wb] = make_float2(0.f, 0.f);
            }
        }
    };
    load_half(0);

    // ---- weight stage ----
    if (USE_WS) {
        // linear copy of the prepped image: zero index math, no conflicts
        const int4* src = (const int4*)wpk;
        int4* dstW = (int4*)&ldsW[0];
        #pragma unroll
        for (int i2 = 0; i2 < 3; ++i2) {
            const int idx = tid + i2 * 512;
            if (idx < WBYTES / 16) dstW[idx] = src[idx];
        }
    } else {
        // fallback (no workspace): in-kernel staging
        for (int i = tid; i < OC_ * C_ * 9; i += 512) {
            const float v = wgt[i];
            const int oc  = i / 288;
            const int rem = i - oc * 288;
            const int ic  = rem / 9;
            const int t9  = rem - ic * 9;
            ldsW[(t9 * 32 + oc) * WSTRD + ic] = f2bf(v);
        }
    }

    // ---- acc init with bias (D row = oc mapping, verified in R2) ----
    float16v acc0, acc1;
    #pragma unroll
    for (int r = 0; r < 16; ++r) {
        const float bv = bias[(r & 3) + 8 * (r >> 2) + 4 * qd];
        acc0[r] = bv;
        acc1[r] = bv;
    }

    auto write_half = [&]() {
        unsigned short* dst = &ldsX[r4 * XROW];
        #pragma unroll
        for (int wb = 0; wb < 4; ++wb) {
            const int w = wb * 64 + 2 * wlo;
            *(unsigned*)&dst[(w + 1) * XSTR + 2 * icq]       = cvtpk(a0[wb].x,  a1[wb].x);
            *(unsigned*)&dst[(w + 2) * XSTR + 2 * icq]       = cvtpk(a0[wb].y,  a1[wb].y);
            *(unsigned*)&dst[(w + 1) * XSTR + 2 * (icq + 4)] = cvtpk(b0r[wb].x, b1r[wb].x);
            *(unsigned*)&dst[(w + 2) * XSTR + 2 * (icq + 4)] = cvtpk(b0r[wb].y, b1r[wb].y);
        }
    };

    auto mfma_half = [&](int half) {
        #pragma unroll
        for (int kh = 0; kh < 3; ++kh) {
            #pragma unroll
            for (int kw = 0; kw < 3; ++kw) {
                const int t9 = kh * 3 + kw;
                const short8v av =
                    load8(&ldsW[(t9 * 32 + col) * WSTRD + half * 16 + qd * 8]);
                const short8v bf0 =
                    load8(&ldsX[(rsel + kh) * XROW + (w0a + col + kw) * XSTR + qd * 8]);
                const short8v bf1 =
                    load8(&ldsX[(rsel + kh) * XROW + (w0b + col + kw) * XSTR + qd * 8]);
                acc0 = __builtin_amdgcn_mfma_f32_32x32x16_bf16(av, bf0, acc0, 0, 0, 0);
                acc1 = __builtin_amdgcn_mfma_f32_32x32x16_bf16(av, bf1, acc1, 0, 0, 0);
            }
        }
    };

    // ---- pack + write half0; halo zeros (persist across both halves) ----
    write_half();
    if (tid < 32) {
        const int r  = tid >> 3;                 // staged row 0..3
        const int q  = tid & 7;
        const int wi = (q & 4) ? 257 : 0;
        const int c  = q & 3;
        *(unsigned long long*)&ldsX[r * XROW + wi * XSTR + c * 4] = 0ull;
    }
    __syncthreads();                 // X0 + W staged

    // half1 loads fly under MFMA half0; barrier #2's vmcnt(0) drains them
    load_half(1);
    mfma_half(0);
    __syncthreads();                 // MFMA0 readers done (and half1 loads landed)

    write_half();
    __syncthreads();                 // X1 staged
    mfma_half(1);

    // ---- epilogue: LDS transpose -> fully contiguous 1KB NT stores ----
    __syncthreads();                 // all frag reads of ldsX done
    float* scr = (float*)&ldsX[0];   // 32 KB scratch: [32 oc][256 w] fp32
    #pragma unroll
    for (int rr = 0; rr < 2; ++rr) {
        if (rsel == rr) {            // wave-uniform branch
            #pragma unroll
            for (int r = 0; r < 16; ++r) {
                const int oc = (r & 3) + 8 * (r >> 2) + 4 * qd;
                scr[oc * 256 + w0a + col] = acc0[r];   // 2-way bank = free
                scr[oc * 256 + w0b + col] = acc1[r];
            }
        }
        __syncthreads();
        // each wave: one full (oc, h+rr) row = 1KB contiguous per instr
        float* outp = out + (size_t)n * OC_ * HW + (size_t)(h + rr) * W_;
        #pragma unroll
        for (int k = 0; k < 4; ++k) {
            const int oc = wv * 4 + k;
            const floatx4 v = *(const floatx4*)&scr[oc * 256 + lane * 4];
            __builtin_nontemporal_store(v, (floatx4*)(outp + (size_t)oc * HW + lane * 4));
        }
        if (rr == 0) __syncthreads();  // row0 stores read scratch before row1 dump
    }
}

extern "C" void kernel_launch(void* const* d_in, const int* in_sizes, int n_in,
                              void* d_out, int out_size, void* d_ws, size_t ws_size,
                              hipStream_t stream) {
    const float* x    = (const float*)d_in[0];
    const float* wgt  = (const float*)d_in[1];
    const float* bias = (const float*)d_in[2];
    float* out        = (float*)d_out;

    dim3 grid(N_ * H_ / 2);   // 2048 blocks: one per (n, h-pair)
    dim3 block(512);

    if (d_ws != nullptr && ws_size >= (size_t)WBYTES) {
        unsigned short* wp = (unsigned short*)d_ws;
        conv_w_prep<<<dim3(36), dim3(256), 0, stream>>>(wgt, wp);
        conv3x3_mfma_kernel<true><<<grid, block, 0, stream>>>(x, wgt, bias, wp, out);
    } else {
        conv3x3_mfma_kernel<false><<<grid, block, 0, stream>>>(x, wgt, bias, nullptr, out);
    }
}